// Round 3
// baseline (809.460 us; speedup 1.0000x reference)
//
#include <hip/hip_runtime.h>
#include <hip/hip_bf16.h>

#define HN 20
#define G4 80
#define EPSC 1e-5f
#define L2E 1.4426950408889634f

typedef float v2f __attribute__((ext_vector_type(2)));

#if __has_builtin(__builtin_amdgcn_exp2f)
#define EXP2(x) __builtin_amdgcn_exp2f(x)
#else
#define EXP2(x) __expf((x) * 0.6931471805599453f)
#endif

// ws layout (floats):
//   [0..79]      Ag   = (A-mean)*g_x[0] * gatescale   (layer-0 x-path slope)
//   [80..159]    Cg   = (C-mean)*g_x[0] * gatescale   (layer-0 x-path intercept)
//   [160..239]   K0   = (be_x+be_h+b_ih+b_hh)[0] * gatescale
//   [240..242]   va, cov, vc  (UNSCALED stats: var(Ax+C) = va x^2 + 2 cov x + vc)
//   [256..1855]  Wihg = centered Wih[1] ⊙ g_x[1] ⊙ gatescale   (80x20)
//   [1856..3455] Whhg = centered Whh[1] ⊙ g_h[1] ⊙ gatescale   (80x20)
//   [3456..3535] K1   = ((be_x+be_h+b_ih+b_hh)[1] + 1_{f-rows}) * gatescale
//   [3536..3935] Gih  = (1/80) Wihc^T Wihc   (20x20, unscaled centered)
//   [3936..4335] Ghh  = (1/80) Whhc^T Whhc
//   [4336..4355] sgc0 = g_c[0]  * 2*L2E      [4356..4375] sbc0 = be_c[0] * 2*L2E
//   [4376..4395] sgc1 = g_c[1]  * 2*L2E      [4396..4415] sbc1 = be_c[1] * 2*L2E
// gatescale(row): i/f/o rows -> L2E (sigmoid), g rows (40..59) -> 2*L2E (tanh)
__global__ void ml_precompute(
    const float* __restrict__ W1, const float* __restrict__ b1,
    const float* __restrict__ Wih, const float* __restrict__ Whh,
    const float* __restrict__ b_ih, const float* __restrict__ b_hh,
    const float* __restrict__ g_x, const float* __restrict__ be_x,
    const float* __restrict__ g_h, const float* __restrict__ be_h,
    const float* __restrict__ g_c, const float* __restrict__ be_c,
    float* __restrict__ ws)
{
    __shared__ float A[G4], C[G4];
    __shared__ float cm[2][HN];
    __shared__ float stats[3];
    __shared__ float Wc[1600], Vc[1600];
    const int t = threadIdx.x;

    if (t < G4) {
        float a = 0.f, c = 0.f;
        for (int k = 0; k < HN; ++k) {
            float w = Wih[t * HN + k];
            a += w * W1[k];
            c += w * b1[k];
        }
        A[t] = a; C[t] = c;
    }
    if (t >= 128 && t < 128 + 2 * HN) {
        int k = (t - 128) % HN;
        const float* src = ((t - 128) < HN) ? (Wih + 1600) : (Whh + 1600);
        float s = 0.f;
        for (int j = 0; j < G4; ++j) s += src[j * HN + k];
        cm[(t - 128) / HN][k] = s * (1.f / 80.f);
    }
    __syncthreads();

    for (int idx = t; idx < 1600; idx += blockDim.x) {
        int k = idx % HN;
        Wc[idx] = Wih[1600 + idx] - cm[0][k];
        Vc[idx] = Whh[1600 + idx] - cm[1][k];
    }
    if (t == 0) {
        float am = 0.f, c_m = 0.f;
        for (int j = 0; j < G4; ++j) { am += A[j]; c_m += C[j]; }
        am *= (1.f / 80.f); c_m *= (1.f / 80.f);
        float va = 0.f, cov = 0.f, vc = 0.f;
        for (int j = 0; j < G4; ++j) {
            float ah = A[j] - am, ch = C[j] - c_m;
            va += ah * ah; cov += ah * ch; vc += ch * ch;
            A[j] = ah; C[j] = ch;
        }
        stats[0] = va * (1.f / 80.f);
        stats[1] = cov * (1.f / 80.f);
        stats[2] = vc * (1.f / 80.f);
    }
    __syncthreads();

    // Gram matrices (unscaled)
    for (int e = t; e < 800; e += blockDim.x) {
        int m = e / 400, kl = e % 400, k = kl / HN, l = kl % HN;
        const float* src = m ? Vc : Wc;
        float s = 0.f;
        for (int j = 0; j < G4; ++j) s += src[j * HN + k] * src[j * HN + l];
        ws[3536 + m * 400 + kl] = s * (1.f / 80.f);
    }
    // gain- and exp2-scaled gate weights
    for (int idx = t; idx < 1600; idx += blockDim.x) {
        int j = idx / HN;
        float sc = (j >= 40 && j < 60) ? (2.f * L2E) : L2E;
        ws[256 + idx]  = Wc[idx] * g_x[80 + j] * sc;
        ws[1856 + idx] = Vc[idx] * g_h[80 + j] * sc;
    }
    if (t < G4) {
        float sc = (t >= 40 && t < 60) ? (2.f * L2E) : L2E;
        ws[t]        = A[t] * g_x[t] * sc;
        ws[80 + t]   = C[t] * g_x[t] * sc;
        ws[160 + t]  = (be_x[t] + be_h[t] + b_ih[t] + b_hh[t]) * sc;
        float k1 = be_x[80 + t] + be_h[80 + t] + b_ih[80 + t] + b_hh[80 + t];
        if (t >= 20 && t < 40) k1 += 1.0f;  // forget-gate bias folded
        ws[3456 + t] = k1 * sc;
    }
    if (t < 3) ws[240 + t] = stats[t];
    if (t < HN) {
        ws[4336 + t] = g_c[t] * (2.f * L2E);
        ws[4356 + t] = be_c[t] * (2.f * L2E);
        ws[4376 + t] = g_c[HN + t] * (2.f * L2E);
        ws[4396 + t] = be_c[HN + t] * (2.f * L2E);
    }
}

// ---------------- main kernel: 1 thread per coordinate ---------------------
// inputs pre-scaled by L2E (sigmoid) / 2*L2E (tanh): pure v_exp_f32, no mul.
__device__ __forceinline__ float sig2(float z) {           // sigmoid(z/L2E)
    return __builtin_amdgcn_rcpf(1.f + EXP2(-z));
}
__device__ __forceinline__ float tanh2(float z) {          // tanh(z/(2*L2E))
    return 1.f - 2.f * __builtin_amdgcn_rcpf(1.f + EXP2(z));
}

// length-20 dot against H[0..9] (v2f pairs); PTR 8B-aligned. Literal indices only.
#define DOT20(RES, PTR) {                                                   \
    const v2f* wp = (const v2f*)(PTR);                                      \
    v2f a_ = __builtin_elementwise_fma(wp[0], H[0], (v2f){0.f, 0.f});       \
    v2f b_ = __builtin_elementwise_fma(wp[1], H[1], (v2f){0.f, 0.f});       \
    a_ = __builtin_elementwise_fma(wp[2], H[2], a_);                        \
    b_ = __builtin_elementwise_fma(wp[3], H[3], b_);                        \
    a_ = __builtin_elementwise_fma(wp[4], H[4], a_);                        \
    b_ = __builtin_elementwise_fma(wp[5], H[5], b_);                        \
    a_ = __builtin_elementwise_fma(wp[6], H[6], a_);                        \
    b_ = __builtin_elementwise_fma(wp[7], H[7], b_);                        \
    a_ = __builtin_elementwise_fma(wp[8], H[8], a_);                        \
    b_ = __builtin_elementwise_fma(wp[9], H[9], b_);                        \
    a_ = a_ + b_;                                                           \
    RES = a_[0] + a_[1];                                                    \
}

__global__ __launch_bounds__(256, 2) void ml_main(
    const float* __restrict__ x_t,
    const float* __restrict__ ws,
    const float* __restrict__ Wo,   // [20]
    const float* __restrict__ bo,   // [1]
    float* __restrict__ out, int n)
{
    const int i = blockIdx.x * blockDim.x + threadIdx.x;
    if (i >= n) return;
    const float x = x_t[i];

    const float* __restrict__ Ag   = ws;
    const float* __restrict__ Cg   = ws + 80;
    const float* __restrict__ K0   = ws + 160;
    const float* __restrict__ Wihg = ws + 256;
    const float* __restrict__ Whhg = ws + 1856;
    const float* __restrict__ K1   = ws + 3456;
    const float* __restrict__ Gih  = ws + 3536;
    const float* __restrict__ Ghh  = ws + 3936;
    const float* __restrict__ sgc0 = ws + 4336;
    const float* __restrict__ sbc0 = ws + 4356;
    const float* __restrict__ sgc1 = ws + 4376;
    const float* __restrict__ sbc1 = ws + 4396;

    const float va = ws[240], cov = ws[241], vc = ws[242];
    const float rs0 = __builtin_amdgcn_rsqf(fmaf(va * x, x, fmaf(2.f * cov, x, vc)) + EPSC);

    // ---- layer 0 (f-gate dead: cx=0) ----
    float c0[HN];
    float mu = 0.f;
#pragma unroll
    for (int k = 0; k < HN; ++k) {
        float zi = fmaf(fmaf(Ag[k], x, Cg[k]), rs0, K0[k]);
        float zg = fmaf(fmaf(Ag[40 + k], x, Cg[40 + k]), rs0, K0[40 + k]);
        float c = sig2(zi) * tanh2(zg);
        c0[k] = c; mu += c;
    }
    mu *= 0.05f;
    float var = 0.f;
#pragma unroll
    for (int k = 0; k < HN; ++k) { float d = c0[k] - mu; var = fmaf(d, d, var); }
    const float rsc = __builtin_amdgcn_rsqf(fmaf(var, 0.05f, EPSC));

    v2f H[10];
#pragma unroll
    for (int k = 0; k < HN; ++k) {
        float zo = fmaf(fmaf(Ag[60 + k], x, Cg[60 + k]), rs0, K0[60 + k]);
        float tn = tanh2(fmaf((c0[k] - mu) * rsc, sgc0[k], sbc0[k]));
        H[k >> 1][k & 1] = sig2(zo) * tn;
    }

    // ---- layer-1 variances via Gram quadratic forms (before the matvec) ----
    float su = 0.f, sv = 0.f;
#pragma unroll
    for (int k = 0; k < HN; ++k) {
        float du, dv;
        DOT20(du, Gih + k * HN);
        DOT20(dv, Ghh + k * HN);
        float hk = H[k >> 1][k & 1];
        su = fmaf(du, hk, su);
        sv = fmaf(dv, hk, sv);
    }
    const float rsu = __builtin_amdgcn_rsqf(su + EPSC);
    const float rsv = __builtin_amdgcn_rsqf(sv + EPSC);

    // ---- layer 1: streamed gates, u/v never stored ----
    float c1[HN], zos[HN];
    float mu1 = 0.f;
#pragma unroll
    for (int k = 0; k < HN; ++k) {
        float dwi, dvi, dwf, dvf, dwg, dvg, dwo, dvo;
        DOT20(dwi, Wihg + k * HN);
        DOT20(dvi, Whhg + k * HN);
        DOT20(dwf, Wihg + (20 + k) * HN);
        DOT20(dvf, Whhg + (20 + k) * HN);
        DOT20(dwg, Wihg + (40 + k) * HN);
        DOT20(dvg, Whhg + (40 + k) * HN);
        DOT20(dwo, Wihg + (60 + k) * HN);
        DOT20(dvo, Whhg + (60 + k) * HN);
        float zi = fmaf(dwi, rsu, fmaf(dvi, rsv, K1[k]));
        float zf = fmaf(dwf, rsu, fmaf(dvf, rsv, K1[20 + k]));
        float zg = fmaf(dwg, rsu, fmaf(dvg, rsv, K1[40 + k]));
        zos[k]   = fmaf(dwo, rsu, fmaf(dvo, rsv, K1[60 + k]));
        float c = sig2(zf) * c0[k] + sig2(zi) * tanh2(zg);
        c1[k] = c; mu1 += c;
    }
    mu1 *= 0.05f;
    float var1 = 0.f;
#pragma unroll
    for (int k = 0; k < HN; ++k) { float d = c1[k] - mu1; var1 = fmaf(d, d, var1); }
    const float rsc1 = __builtin_amdgcn_rsqf(fmaf(var1, 0.05f, EPSC));

    float acc = bo[0];
#pragma unroll
    for (int k = 0; k < HN; ++k) {
        float tn = tanh2(fmaf((c1[k] - mu1) * rsc1, sgc1[k], sbc1[k]));
        acc = fmaf(sig2(zos[k]) * tn, Wo[k], acc);
    }
    out[i] = acc;
}

extern "C" void kernel_launch(void* const* d_in, const int* in_sizes, int n_in,
                              void* d_out, int out_size, void* d_ws, size_t ws_size,
                              hipStream_t stream) {
    const float* x_t  = (const float*)d_in[0];
    const float* W1   = (const float*)d_in[1];
    const float* b1   = (const float*)d_in[2];
    const float* Wih  = (const float*)d_in[3];
    const float* Whh  = (const float*)d_in[4];
    const float* b_ih = (const float*)d_in[5];
    const float* b_hh = (const float*)d_in[6];
    const float* g_x  = (const float*)d_in[7];
    const float* be_x = (const float*)d_in[8];
    const float* g_h  = (const float*)d_in[9];
    const float* be_h = (const float*)d_in[10];
    const float* g_c  = (const float*)d_in[11];
    const float* be_c = (const float*)d_in[12];
    const float* Wo   = (const float*)d_in[13];
    const float* bo   = (const float*)d_in[14];
    float* out = (float*)d_out;
    float* ws  = (float*)d_ws;
    const int n = in_sizes[0];

    hipLaunchKernelGGL(ml_precompute, dim3(1), dim3(256), 0, stream,
                       W1, b1, Wih, Whh, b_ih, b_hh, g_x, be_x, g_h, be_h, g_c, be_c, ws);
    const int blocks = (n + 255) / 256;
    hipLaunchKernelGGL(ml_main, dim3(blocks), dim3(256), 0, stream,
                       x_t, ws, Wo, bo, out, n);
}

// Round 4
// 207.924 us; speedup vs baseline: 3.8931x; 3.8931x over previous
//
#include <hip/hip_runtime.h>

#define HN 20
#define G4 80
#define EPSC 1e-5f
#define L2E 1.4426950408889634f

typedef float v2f __attribute__((ext_vector_type(2)));

#if __has_builtin(__builtin_amdgcn_exp2f)
#define EXP2(x) __builtin_amdgcn_exp2f(x)
#else
#define EXP2(x) __expf((x) * 0.6931471805599453f)
#endif
#define RCP(x) __builtin_amdgcn_rcpf(x)
#define RSQ(x) __builtin_amdgcn_rsqf(x)
// z pre-scaled by -L2E  -> SIG2(z) = sigmoid(z_orig)
#define SIG2(z) RCP(1.f + EXP2(z))
// z pre-scaled by +2*L2E -> TANH2(z) = tanh(z_orig)
#define TANH2(z) fmaf(-2.f, RCP(1.f + EXP2(z)), 1.f)

// ws layout (floats):
//   [0..79]      Ag   = (A-mean)*g_x[0]*sc      (sc: i/f/o rows -L2E, g rows +2L2E)
//   [80..159]    Cg   = (C-mean)*g_x[0]*sc
//   [160..239]   K0   = (be_x+be_h+b_ih+b_hh)[0]*sc
//   [240..242]   va, cov, vc  (unscaled: var(Ax+C) = va x^2 + 2 cov x + vc)
//   [256..1855]  Wihg = centered Wih[1] ⊙ g_x[1] ⊙ sc   (80x20)
//   [1856..3455] Whhg = centered Whh[1] ⊙ g_h[1] ⊙ sc   (80x20)
//   [3456..3535] K1   = ((be_x+be_h+b_ih+b_hh)[1] + 1_{f-rows})*sc
//   [3536..3935] Gih  = (1/80) Wihc^T Wihc   (20x20, unscaled centered)
//   [3936..4335] Ghh  = (1/80) Whhc^T Whhc
//   [4336..4355] sgc0=g_c[0]*2L2E   [4356..4375] sbc0=be_c[0]*2L2E
//   [4376..4395] sgc1=g_c[1]*2L2E   [4396..4415] sbc1=be_c[1]*2L2E
__global__ void ml_precompute(
    const float* __restrict__ W1, const float* __restrict__ b1,
    const float* __restrict__ Wih, const float* __restrict__ Whh,
    const float* __restrict__ b_ih, const float* __restrict__ b_hh,
    const float* __restrict__ g_x, const float* __restrict__ be_x,
    const float* __restrict__ g_h, const float* __restrict__ be_h,
    const float* __restrict__ g_c, const float* __restrict__ be_c,
    float* __restrict__ ws)
{
    __shared__ float A[G4], C[G4];
    __shared__ float cm[2][HN];
    __shared__ float stats[3];
    __shared__ float Wc[1600], Vc[1600];
    const int t = threadIdx.x;

    if (t < G4) {
        float a = 0.f, c = 0.f;
        for (int k = 0; k < HN; ++k) {
            float w = Wih[t * HN + k];
            a += w * W1[k];
            c += w * b1[k];
        }
        A[t] = a; C[t] = c;
    }
    if (t >= 128 && t < 128 + 2 * HN) {
        int k = (t - 128) % HN;
        const float* src = ((t - 128) < HN) ? (Wih + 1600) : (Whh + 1600);
        float s = 0.f;
        for (int j = 0; j < G4; ++j) s += src[j * HN + k];
        cm[(t - 128) / HN][k] = s * (1.f / 80.f);
    }
    __syncthreads();

    for (int idx = t; idx < 1600; idx += blockDim.x) {
        int k = idx % HN;
        Wc[idx] = Wih[1600 + idx] - cm[0][k];
        Vc[idx] = Whh[1600 + idx] - cm[1][k];
    }
    if (t == 0) {
        float am = 0.f, c_m = 0.f;
        for (int j = 0; j < G4; ++j) { am += A[j]; c_m += C[j]; }
        am *= (1.f / 80.f); c_m *= (1.f / 80.f);
        float va = 0.f, cov = 0.f, vc = 0.f;
        for (int j = 0; j < G4; ++j) {
            float ah = A[j] - am, ch = C[j] - c_m;
            va += ah * ah; cov += ah * ch; vc += ch * ch;
            A[j] = ah; C[j] = ch;
        }
        stats[0] = va * (1.f / 80.f);
        stats[1] = cov * (1.f / 80.f);
        stats[2] = vc * (1.f / 80.f);
    }
    __syncthreads();

    // Gram matrices (unscaled centered)
    for (int e = t; e < 800; e += blockDim.x) {
        int m = e / 400, kl = e % 400, k = kl / HN, l = kl % HN;
        const float* src = m ? Vc : Wc;
        float s = 0.f;
        for (int j = 0; j < G4; ++j) s += src[j * HN + k] * src[j * HN + l];
        ws[3536 + m * 400 + kl] = s * (1.f / 80.f);
    }
    // gain-, sign-, and exp2-scaled gate weights
    for (int idx = t; idx < 1600; idx += blockDim.x) {
        int j = idx / HN;
        float sc = (j >= 40 && j < 60) ? (2.f * L2E) : (-L2E);
        ws[256 + idx]  = Wc[idx] * g_x[80 + j] * sc;
        ws[1856 + idx] = Vc[idx] * g_h[80 + j] * sc;
    }
    if (t < G4) {
        float sc = (t >= 40 && t < 60) ? (2.f * L2E) : (-L2E);
        ws[t]        = A[t] * g_x[t] * sc;
        ws[80 + t]   = C[t] * g_x[t] * sc;
        ws[160 + t]  = (be_x[t] + be_h[t] + b_ih[t] + b_hh[t]) * sc;
        float k1 = be_x[80 + t] + be_h[80 + t] + b_ih[80 + t] + b_hh[80 + t];
        if (t >= 20 && t < 40) k1 += 1.0f;  // forget-gate bias folded
        ws[3456 + t] = k1 * sc;
    }
    if (t < 3) ws[240 + t] = stats[t];
    if (t < HN) {
        ws[4336 + t] = g_c[t] * (2.f * L2E);
        ws[4356 + t] = be_c[t] * (2.f * L2E);
        ws[4376 + t] = g_c[HN + t] * (2.f * L2E);
        ws[4396 + t] = be_c[HN + t] * (2.f * L2E);
    }
}

// ---------------- main kernel: 1 thread per coordinate ---------------------
// ALL per-thread state is named SSA scalars (no arrays -> nothing can spill
// to scratch via failed SROA). Repetition via macros; every index literal.
#define REP20(M) M(0) M(1) M(2) M(3) M(4) M(5) M(6) M(7) M(8) M(9) \
                 M(10) M(11) M(12) M(13) M(14) M(15) M(16) M(17) M(18) M(19)

// length-20 dot of uniform weights (8B-aligned rows) against Hp0..Hp9
#define DOT20(RES, BASE) {                                                  \
    const v2f* wp_ = (const v2f*)(BASE);                                    \
    v2f a_ = __builtin_elementwise_fma(wp_[0], Hp0, (v2f){0.f, 0.f});       \
    v2f b_ = __builtin_elementwise_fma(wp_[1], Hp1, (v2f){0.f, 0.f});       \
    a_ = __builtin_elementwise_fma(wp_[2], Hp2, a_);                        \
    b_ = __builtin_elementwise_fma(wp_[3], Hp3, b_);                        \
    a_ = __builtin_elementwise_fma(wp_[4], Hp4, a_);                        \
    b_ = __builtin_elementwise_fma(wp_[5], Hp5, b_);                        \
    a_ = __builtin_elementwise_fma(wp_[6], Hp6, a_);                        \
    b_ = __builtin_elementwise_fma(wp_[7], Hp7, b_);                        \
    a_ = __builtin_elementwise_fma(wp_[8], Hp8, a_);                        \
    b_ = __builtin_elementwise_fma(wp_[9], Hp9, b_);                        \
    a_ = a_ + b_;                                                           \
    RES = a_[0] + a_[1]; }

__global__ __launch_bounds__(256, 3) void ml_main(
    const float* __restrict__ x_t,
    const float* __restrict__ ws,
    const float* __restrict__ Wo,   // [20]
    const float* __restrict__ bo,   // [1]
    float* __restrict__ out, int n)
{
    const int i = blockIdx.x * blockDim.x + threadIdx.x;
    if (i >= n) return;
    const float x = x_t[i];

    const float* __restrict__ Ag   = ws;
    const float* __restrict__ Cg   = ws + 80;
    const float* __restrict__ K0   = ws + 160;
    const float* __restrict__ Wihg = ws + 256;
    const float* __restrict__ Whhg = ws + 1856;
    const float* __restrict__ K1   = ws + 3456;
    const float* __restrict__ Gih  = ws + 3536;
    const float* __restrict__ Ghh  = ws + 3936;
    const float* __restrict__ sgc0 = ws + 4336;
    const float* __restrict__ sbc0 = ws + 4356;
    const float* __restrict__ sgc1 = ws + 4376;
    const float* __restrict__ sbc1 = ws + 4396;

    const float va = ws[240], cov = ws[241], vc = ws[242];
    const float rs0 = RSQ(fmaf(va * x, x, fmaf(2.f * cov, x, vc)) + EPSC);

    // ---- layer 0 (f-gate dead: cx=0) ----
    float mu = 0.f;
#define L0A(k) float c0_##k; {                                              \
    float zi_ = fmaf(fmaf(Ag[k], x, Cg[k]), rs0, K0[k]);                    \
    float zg_ = fmaf(fmaf(Ag[40 + k], x, Cg[40 + k]), rs0, K0[40 + k]);     \
    c0_##k = SIG2(zi_) * TANH2(zg_); mu += c0_##k; }
    REP20(L0A)
    mu *= 0.05f;
    float var = 0.f;
#define L0V(k) { float d_ = c0_##k - mu; var = fmaf(d_, d_, var); }
    REP20(L0V)
    const float rsc = RSQ(fmaf(var, 0.05f, EPSC));
#define L0B(k) float h_##k; {                                               \
    float zo_ = fmaf(fmaf(Ag[60 + k], x, Cg[60 + k]), rs0, K0[60 + k]);     \
    float tn_ = TANH2(fmaf((c0_##k - mu) * rsc, sgc0[k], sbc0[k]));         \
    h_##k = SIG2(zo_) * tn_; }
    REP20(L0B)

    const v2f Hp0 = {h_0,  h_1};  const v2f Hp1 = {h_2,  h_3};
    const v2f Hp2 = {h_4,  h_5};  const v2f Hp3 = {h_6,  h_7};
    const v2f Hp4 = {h_8,  h_9};  const v2f Hp5 = {h_10, h_11};
    const v2f Hp6 = {h_12, h_13}; const v2f Hp7 = {h_14, h_15};
    const v2f Hp8 = {h_16, h_17}; const v2f Hp9 = {h_18, h_19};

    // ---- layer-1 variances via Gram quadratic forms (before the matvec) ----
    float su = 0.f, sv = 0.f;
#define GRAMK(k) { float du_, dv_;                                          \
    DOT20(du_, Gih + k * HN); DOT20(dv_, Ghh + k * HN);                     \
    su = fmaf(du_, h_##k, su); sv = fmaf(dv_, h_##k, sv); }
    REP20(GRAMK)
    const float rsu = RSQ(su + EPSC);
    const float rsv = RSQ(sv + EPSC);

    // ---- layer 1: streamed gates, u/v never stored ----
    float mu1 = 0.f;
#define G1(k) float c1_##k, zo_##k; {                                       \
    float dwi_, dvi_, dwf_, dvf_, dwg_, dvg_, dwo_, dvo_;                   \
    DOT20(dwi_, Wihg + k * HN);        DOT20(dvi_, Whhg + k * HN);          \
    DOT20(dwf_, Wihg + (20 + k) * HN); DOT20(dvf_, Whhg + (20 + k) * HN);   \
    DOT20(dwg_, Wihg + (40 + k) * HN); DOT20(dvg_, Whhg + (40 + k) * HN);   \
    DOT20(dwo_, Wihg + (60 + k) * HN); DOT20(dvo_, Whhg + (60 + k) * HN);   \
    float zi_ = fmaf(dwi_, rsu, fmaf(dvi_, rsv, K1[k]));                    \
    float zf_ = fmaf(dwf_, rsu, fmaf(dvf_, rsv, K1[20 + k]));               \
    float zg_ = fmaf(dwg_, rsu, fmaf(dvg_, rsv, K1[40 + k]));               \
    zo_##k    = fmaf(dwo_, rsu, fmaf(dvo_, rsv, K1[60 + k]));               \
    c1_##k = fmaf(SIG2(zf_), c0_##k, SIG2(zi_) * TANH2(zg_));               \
    mu1 += c1_##k; }
    REP20(G1)
    mu1 *= 0.05f;
    float var1 = 0.f;
#define V1(k) { float d_ = c1_##k - mu1; var1 = fmaf(d_, d_, var1); }
    REP20(V1)
    const float rsc1 = RSQ(fmaf(var1, 0.05f, EPSC));

    float acc = bo[0];
#define OUTK(k) {                                                           \
    float tn_ = TANH2(fmaf((c1_##k - mu1) * rsc1, sgc1[k], sbc1[k]));       \
    acc = fmaf(SIG2(zo_##k) * tn_, Wo[k], acc); }
    REP20(OUTK)
    out[i] = acc;
}

extern "C" void kernel_launch(void* const* d_in, const int* in_sizes, int n_in,
                              void* d_out, int out_size, void* d_ws, size_t ws_size,
                              hipStream_t stream) {
    const float* x_t  = (const float*)d_in[0];
    const float* W1   = (const float*)d_in[1];
    const float* b1   = (const float*)d_in[2];
    const float* Wih  = (const float*)d_in[3];
    const float* Whh  = (const float*)d_in[4];
    const float* b_ih = (const float*)d_in[5];
    const float* b_hh = (const float*)d_in[6];
    const float* g_x  = (const float*)d_in[7];
    const float* be_x = (const float*)d_in[8];
    const float* g_h  = (const float*)d_in[9];
    const float* be_h = (const float*)d_in[10];
    const float* g_c  = (const float*)d_in[11];
    const float* be_c = (const float*)d_in[12];
    const float* Wo   = (const float*)d_in[13];
    const float* bo   = (const float*)d_in[14];
    float* out = (float*)d_out;
    float* ws  = (float*)d_ws;
    const int n = in_sizes[0];

    hipLaunchKernelGGL(ml_precompute, dim3(1), dim3(256), 0, stream,
                       W1, b1, Wih, Whh, b_ih, b_hh, g_x, be_x, g_h, be_h, g_c, be_c, ws);
    const int blocks = (n + 255) / 256;
    hipLaunchKernelGGL(ml_main, dim3(blocks), dim3(256), 0, stream,
                       x_t, ws, Wo, bo, out, n);
}

// Round 5
// 145.402 us; speedup vs baseline: 5.5671x; 1.4300x over previous
//
#include <hip/hip_runtime.h>

#define HN 20
#define G4 80
#define EPSC 1e-5f
#define L2E 1.4426950408889634f

typedef float v2f __attribute__((ext_vector_type(2)));

#if __has_builtin(__builtin_amdgcn_exp2f)
#define EXP2(x) __builtin_amdgcn_exp2f(x)
#else
#define EXP2(x) __expf((x) * 0.6931471805599453f)
#endif
#define RCP(x) __builtin_amdgcn_rcpf(x)
#define RSQ(x) __builtin_amdgcn_rsqf(x)
// z pre-scaled by -L2E  -> SIG2(z) = sigmoid(z_orig)
#define SIG2(z) RCP(1.f + EXP2(z))
// z pre-scaled by +2*L2E -> TANH2(z) = tanh(z_orig)
#define TANH2(z) fmaf(-2.f, RCP(1.f + EXP2(z)), 1.f)

// ws layout (floats):
//   [0..79]      Ag   = (A-mean)*g_x[0]*sc      (sc: i/f/o rows -L2E, g rows +2L2E)
//   [80..159]    Cg   = (C-mean)*g_x[0]*sc
//   [160..239]   K0   = (be_x+be_h+b_ih+b_hh)[0]*sc
//   [240..242]   va, cov, vc  (unscaled: var(Ax+C) = va x^2 + 2 cov x + vc)
//   [256..1855]  Wihg = centered Wih[1] ⊙ g_x[1] ⊙ sc   (80x20)
//   [1856..3455] Whhg = centered Whh[1] ⊙ g_h[1] ⊙ sc   (80x20)
//   [3456..3535] K1   = ((be_x+be_h+b_ih+b_hh)[1] + 1_{f-rows})*sc
//   [3536..3935] Gih  = (1/80) Wihc^T Wihc   (20x20, unscaled centered)
//   [3936..4335] Ghh  = (1/80) Whhc^T Whhc
//   [4336..4355] sgc0=g_c[0]*2L2E   [4356..4375] sbc0=be_c[0]*2L2E
//   [4376..4395] sgc1=g_c[1]*2L2E   [4396..4415] sbc1=be_c[1]*2L2E
__global__ void ml_precompute(
    const float* __restrict__ W1, const float* __restrict__ b1,
    const float* __restrict__ Wih, const float* __restrict__ Whh,
    const float* __restrict__ b_ih, const float* __restrict__ b_hh,
    const float* __restrict__ g_x, const float* __restrict__ be_x,
    const float* __restrict__ g_h, const float* __restrict__ be_h,
    const float* __restrict__ g_c, const float* __restrict__ be_c,
    float* __restrict__ ws)
{
    __shared__ float A[G4], C[G4];
    __shared__ float cm[2][HN];
    __shared__ float stats[3];
    __shared__ float Wc[1600], Vc[1600];
    const int t = threadIdx.x;

    if (t < G4) {
        float a = 0.f, c = 0.f;
        for (int k = 0; k < HN; ++k) {
            float w = Wih[t * HN + k];
            a += w * W1[k];
            c += w * b1[k];
        }
        A[t] = a; C[t] = c;
    }
    if (t >= 128 && t < 128 + 2 * HN) {
        int k = (t - 128) % HN;
        const float* src = ((t - 128) < HN) ? (Wih + 1600) : (Whh + 1600);
        float s = 0.f;
        for (int j = 0; j < G4; ++j) s += src[j * HN + k];
        cm[(t - 128) / HN][k] = s * (1.f / 80.f);
    }
    __syncthreads();

    for (int idx = t; idx < 1600; idx += blockDim.x) {
        int k = idx % HN;
        Wc[idx] = Wih[1600 + idx] - cm[0][k];
        Vc[idx] = Whh[1600 + idx] - cm[1][k];
    }
    if (t == 0) {
        float am = 0.f, c_m = 0.f;
        for (int j = 0; j < G4; ++j) { am += A[j]; c_m += C[j]; }
        am *= (1.f / 80.f); c_m *= (1.f / 80.f);
        float va = 0.f, cov = 0.f, vc = 0.f;
        for (int j = 0; j < G4; ++j) {
            float ah = A[j] - am, ch = C[j] - c_m;
            va += ah * ah; cov += ah * ch; vc += ch * ch;
            A[j] = ah; C[j] = ch;
        }
        stats[0] = va * (1.f / 80.f);
        stats[1] = cov * (1.f / 80.f);
        stats[2] = vc * (1.f / 80.f);
    }
    __syncthreads();

    // Gram matrices (unscaled centered)
    for (int e = t; e < 800; e += blockDim.x) {
        int m = e / 400, kl = e % 400, k = kl / HN, l = kl % HN;
        const float* src = m ? Vc : Wc;
        float s = 0.f;
        for (int j = 0; j < G4; ++j) s += src[j * HN + k] * src[j * HN + l];
        ws[3536 + m * 400 + kl] = s * (1.f / 80.f);
    }
    // gain-, sign-, and exp2-scaled gate weights
    for (int idx = t; idx < 1600; idx += blockDim.x) {
        int j = idx / HN;
        float sc = (j >= 40 && j < 60) ? (2.f * L2E) : (-L2E);
        ws[256 + idx]  = Wc[idx] * g_x[80 + j] * sc;
        ws[1856 + idx] = Vc[idx] * g_h[80 + j] * sc;
    }
    if (t < G4) {
        float sc = (t >= 40 && t < 60) ? (2.f * L2E) : (-L2E);
        ws[t]        = A[t] * g_x[t] * sc;
        ws[80 + t]   = C[t] * g_x[t] * sc;
        ws[160 + t]  = (be_x[t] + be_h[t] + b_ih[t] + b_hh[t]) * sc;
        float k1 = be_x[80 + t] + be_h[80 + t] + b_ih[80 + t] + b_hh[80 + t];
        if (t >= 20 && t < 40) k1 += 1.0f;  // forget-gate bias folded
        ws[3456 + t] = k1 * sc;
    }
    if (t < 3) ws[240 + t] = stats[t];
    if (t < HN) {
        ws[4336 + t] = g_c[t] * (2.f * L2E);
        ws[4356 + t] = be_c[t] * (2.f * L2E);
        ws[4376 + t] = g_c[HN + t] * (2.f * L2E);
        ws[4396 + t] = be_c[HN + t] * (2.f * L2E);
    }
}

// ---------------- main kernel: 1 thread per coordinate ---------------------
// Register pressure bounded BY CONSTRUCTION: runtime-indexed per-thread state
// lives in LDS (SoA: slot*256+tid -> lane-contiguous, 2-way bank alias = free).
// Registers hold only Hp0..Hp9 (h, loop-invariant) + short-lived temps.
#define REP20(M) M(0) M(1) M(2) M(3) M(4) M(5) M(6) M(7) M(8) M(9) \
                 M(10) M(11) M(12) M(13) M(14) M(15) M(16) M(17) M(18) M(19)

// length-20 dot of uniform weights (8B-aligned rows) against Hp0..Hp9
#define DOT20(RES, BASE) {                                                  \
    const v2f* wp_ = (const v2f*)(BASE);                                    \
    v2f a_ = __builtin_elementwise_fma(wp_[0], Hp0, (v2f){0.f, 0.f});       \
    v2f b_ = __builtin_elementwise_fma(wp_[1], Hp1, (v2f){0.f, 0.f});       \
    a_ = __builtin_elementwise_fma(wp_[2], Hp2, a_);                        \
    b_ = __builtin_elementwise_fma(wp_[3], Hp3, b_);                        \
    a_ = __builtin_elementwise_fma(wp_[4], Hp4, a_);                        \
    b_ = __builtin_elementwise_fma(wp_[5], Hp5, b_);                        \
    a_ = __builtin_elementwise_fma(wp_[6], Hp6, a_);                        \
    b_ = __builtin_elementwise_fma(wp_[7], Hp7, b_);                        \
    a_ = __builtin_elementwise_fma(wp_[8], Hp8, a_);                        \
    b_ = __builtin_elementwise_fma(wp_[9], Hp9, b_);                        \
    a_ = a_ + b_;                                                           \
    RES = a_[0] + a_[1]; }

__global__ __launch_bounds__(256, 2) void ml_main(
    const float* __restrict__ x_t,
    const float* __restrict__ ws,
    const float* __restrict__ Wo,   // [20]
    const float* __restrict__ bo,   // [1]
    float* __restrict__ out, int n)
{
    // per-thread state in LDS: CS = c0 (then overwritten in-place by c1), ZS = zo
    __shared__ float CS[HN * 256];
    __shared__ float ZS[HN * 256];
    const int tid = threadIdx.x;
    const int i = blockIdx.x * blockDim.x + tid;
    if (i >= n) return;
    const float x = x_t[i];

    const float* __restrict__ Ag   = ws;
    const float* __restrict__ Cg   = ws + 80;
    const float* __restrict__ K0   = ws + 160;
    const float* __restrict__ Wihg = ws + 256;
    const float* __restrict__ Whhg = ws + 1856;
    const float* __restrict__ K1   = ws + 3456;
    const float* __restrict__ Gih  = ws + 3536;
    const float* __restrict__ Ghh  = ws + 3936;
    const float* __restrict__ sgc0 = ws + 4336;
    const float* __restrict__ sbc0 = ws + 4356;
    const float* __restrict__ sgc1 = ws + 4376;
    const float* __restrict__ sbc1 = ws + 4396;

    const float va = ws[240], cov = ws[241], vc = ws[242];
    const float rs0 = RSQ(fmaf(va * x, x, fmaf(2.f * cov, x, vc)) + EPSC);

    // ---- layer 0 (f-gate dead: cx=0); static, short-lived named scalars ----
    float mu = 0.f, m2 = 0.f;
#define L0A(k) float c0_##k; {                                              \
    float zi_ = fmaf(fmaf(Ag[k], x, Cg[k]), rs0, K0[k]);                    \
    float zg_ = fmaf(fmaf(Ag[40 + k], x, Cg[40 + k]), rs0, K0[40 + k]);     \
    c0_##k = SIG2(zi_) * TANH2(zg_);                                        \
    mu += c0_##k; m2 = fmaf(c0_##k, c0_##k, m2); }
    REP20(L0A)
    mu *= 0.05f;
    const float rsc = RSQ(fmaf(m2, 0.05f, -mu * mu) + EPSC);
#define L0B(k) float h_##k; {                                               \
    float zo_ = fmaf(fmaf(Ag[60 + k], x, Cg[60 + k]), rs0, K0[60 + k]);     \
    float tn_ = TANH2(fmaf((c0_##k - mu) * rsc, sgc0[k], sbc0[k]));         \
    h_##k = SIG2(zo_) * tn_;                                                \
    CS[k * 256 + tid] = c0_##k; }
    REP20(L0B)

    const v2f Hp0 = {h_0,  h_1};  const v2f Hp1 = {h_2,  h_3};
    const v2f Hp2 = {h_4,  h_5};  const v2f Hp3 = {h_6,  h_7};
    const v2f Hp4 = {h_8,  h_9};  const v2f Hp5 = {h_10, h_11};
    const v2f Hp6 = {h_12, h_13}; const v2f Hp7 = {h_14, h_15};
    const v2f Hp8 = {h_16, h_17}; const v2f Hp9 = {h_18, h_19};

    // ---- layer-1 variances via Gram quadratic forms (static; h_k named) ----
    float su = 0.f, sv = 0.f;
#define GRAMK(k) { float du_, dv_;                                          \
    DOT20(du_, Gih + k * HN); DOT20(dv_, Ghh + k * HN);                     \
    su = fmaf(du_, h_##k, su); sv = fmaf(dv_, h_##k, sv); }
    REP20(GRAMK)
    const float rsu = RSQ(su + EPSC);
    const float rsv = RSQ(sv + EPSC);

    // ---- layer 1: rolled loop, state via LDS; c1 overwrites c0 in place ----
    float mu1 = 0.f, m21 = 0.f;
#pragma unroll 2
    for (int k = 0; k < HN; ++k) {
        float dwi_, dvi_, dwf_, dvf_, dwg_, dvg_, dwo_, dvo_;
        DOT20(dwi_, Wihg + k * HN);        DOT20(dvi_, Whhg + k * HN);
        DOT20(dwf_, Wihg + (20 + k) * HN); DOT20(dvf_, Whhg + (20 + k) * HN);
        DOT20(dwg_, Wihg + (40 + k) * HN); DOT20(dvg_, Whhg + (40 + k) * HN);
        DOT20(dwo_, Wihg + (60 + k) * HN); DOT20(dvo_, Whhg + (60 + k) * HN);
        float zi_ = fmaf(dwi_, rsu, fmaf(dvi_, rsv, K1[k]));
        float zf_ = fmaf(dwf_, rsu, fmaf(dvf_, rsv, K1[20 + k]));
        float zg_ = fmaf(dwg_, rsu, fmaf(dvg_, rsv, K1[40 + k]));
        float zo_ = fmaf(dwo_, rsu, fmaf(dvo_, rsv, K1[60 + k]));
        float c0k = CS[k * 256 + tid];
        float c1k = fmaf(SIG2(zf_), c0k, SIG2(zi_) * TANH2(zg_));
        CS[k * 256 + tid] = c1k;       // c0[k] dead after this iteration
        ZS[k * 256 + tid] = zo_;
        mu1 += c1k; m21 = fmaf(c1k, c1k, m21);
    }
    mu1 *= 0.05f;
    const float rsc1 = RSQ(fmaf(m21, 0.05f, -mu1 * mu1) + EPSC);

    float acc = bo[0];
#pragma unroll 2
    for (int k = 0; k < HN; ++k) {
        float c1k = CS[k * 256 + tid];
        float zok = ZS[k * 256 + tid];
        float tn_ = TANH2(fmaf((c1k - mu1) * rsc1, sgc1[k], sbc1[k]));
        acc = fmaf(SIG2(zok) * tn_, Wo[k], acc);
    }
    out[i] = acc;
}

extern "C" void kernel_launch(void* const* d_in, const int* in_sizes, int n_in,
                              void* d_out, int out_size, void* d_ws, size_t ws_size,
                              hipStream_t stream) {
    const float* x_t  = (const float*)d_in[0];
    const float* W1   = (const float*)d_in[1];
    const float* b1   = (const float*)d_in[2];
    const float* Wih  = (const float*)d_in[3];
    const float* Whh  = (const float*)d_in[4];
    const float* b_ih = (const float*)d_in[5];
    const float* b_hh = (const float*)d_in[6];
    const float* g_x  = (const float*)d_in[7];
    const float* be_x = (const float*)d_in[8];
    const float* g_h  = (const float*)d_in[9];
    const float* be_h = (const float*)d_in[10];
    const float* g_c  = (const float*)d_in[11];
    const float* be_c = (const float*)d_in[12];
    const float* Wo   = (const float*)d_in[13];
    const float* bo   = (const float*)d_in[14];
    float* out = (float*)d_out;
    float* ws  = (float*)d_ws;
    const int n = in_sizes[0];

    hipLaunchKernelGGL(ml_precompute, dim3(1), dim3(256), 0, stream,
                       W1, b1, Wih, Whh, b_ih, b_hh, g_x, be_x, g_h, be_h, g_c, be_c, ws);
    const int blocks = (n + 255) / 256;
    hipLaunchKernelGGL(ml_main, dim3(blocks), dim3(256), 0, stream,
                       x_t, ws, Wo, bo, out, n);
}